// Round 5
// baseline (1654.513 us; speedup 1.0000x reference)
//
#include <hip/hip_runtime.h>

// Graphormer encoder — single persistent mega-kernel, hierarchical grid barrier.
// R13: R12 ran at 1 block/CU (Occupancy 12%) -> all stages latency-bound.
// GRID 256 -> 1024 with __launch_bounds__(256,4): 4 blocks/CU co-resident
// (VGPR 128, LDS 32KB x4 = 128KB <= 160KB). Barrier tree 32 groups x 32
// blocks, 256B line separation, relaxed polls + single release/acquire fences.

#define NG   64
#define NP   31
#define NORI 1984
#define NT   2048
#define DIM  512
#define NHD  8
#define DKH  64
#define FFD  2048
#define NLAY 4
#define NFEA 32
#define GRID 1024
#define GSH  5          // log2(blocks per group) = 32 blocks/group, 32 groups

typedef __attribute__((ext_vector_type(8))) short short8;
typedef __attribute__((ext_vector_type(4))) float floatx4;

__device__ __forceinline__ unsigned short f2bf(float f) {
    union { float f; unsigned u; } v; v.f = f;
    unsigned r = v.u + 0x7fffu + ((v.u >> 16) & 1u);
    return (unsigned short)(r >> 16);
}
__device__ __forceinline__ float bf2f(unsigned short u) {
    union { unsigned u; float f; } v; v.u = ((unsigned)u) << 16;
    return v.f;
}

struct MP {
    const float* x; const int* sp; const int* degrees;
    const float* init_W; const float* init_b; const float* cent_emb;
    const float* db; const float* vbias;
    const float* Wq; const float* Wk; const float* Wv;
    const float* bq; const float* bk; const float* bv;
    const float* Wo; const float* bo; const float* W1; const float* b1;
    const float* W2; const float* b2;
    float* h; unsigned short* hn; unsigned short* o; unsigned short* qkv;
    float* Bg;
    unsigned short* Wqkv_t; unsigned short* Wo_t; unsigned short* W1_t; unsigned short* W2_t;
    float* bqkv;
    unsigned* bar;
    float* out;
};

// ---------------------------------------------------------------- grid barrier
// Monotonic 2-level counters. Group g: cnt=bar[g*64], gen=bar[g*64+32].
// Root: cnt=bar[2048], gen=bar[2048+32]. Epoch e: leaf target e*32, root e*32.
__device__ __forceinline__ void gbar(unsigned* bar, unsigned e)
{
    __syncthreads();
    if (threadIdx.x == 0) {
        __builtin_amdgcn_fence(__ATOMIC_RELEASE, "agent");      // writeback
        int g = blockIdx.x >> GSH;
        unsigned* leafc = bar + g * 64;
        unsigned* leafg = bar + g * 64 + 32;
        unsigned* rootc = bar + 2048;
        unsigned* rootg = bar + 2048 + 32;
        unsigned t = __hip_atomic_fetch_add(leafc, 1u, __ATOMIC_RELAXED,
                                            __HIP_MEMORY_SCOPE_AGENT) + 1u;
        if (t == (e << GSH)) {                     // last of 32 in group
            unsigned r = __hip_atomic_fetch_add(rootc, 1u, __ATOMIC_RELAXED,
                                                __HIP_MEMORY_SCOPE_AGENT) + 1u;
            if (r == (e << 5)) {                   // last of 32 groups
                __hip_atomic_fetch_add(rootg, 1u, __ATOMIC_RELAXED,
                                       __HIP_MEMORY_SCOPE_AGENT);
            } else {
                while (__hip_atomic_load(rootg, __ATOMIC_RELAXED,
                                         __HIP_MEMORY_SCOPE_AGENT) < e)
                    __builtin_amdgcn_s_sleep(1);
            }
            __hip_atomic_fetch_add(leafg, 1u, __ATOMIC_RELAXED,
                                   __HIP_MEMORY_SCOPE_AGENT);
        } else {
            while (__hip_atomic_load(leafg, __ATOMIC_RELAXED,
                                     __HIP_MEMORY_SCOPE_AGENT) < e)
                __builtin_amdgcn_s_sleep(1);
        }
        __builtin_amdgcn_fence(__ATOMIC_ACQUIRE, "agent");      // invalidate
    }
    __syncthreads();
}

__global__ void bar_init(unsigned* bar) {
    for (int i = threadIdx.x; i < 4096; i += 256) bar[i] = 0u;
}

// ---------------------------------------------------------------- prep units
__device__ __forceinline__ void prep_inith_unit(const MP& p, int n, char* smem)
{
    int tid = threadIdx.x;
    if (n >= NT) {               // build_B: one unit per graph
        int g = n - NT;
        float vb = p.vbias[0];
        for (int e = tid; e < 1024; e += 256) {
            int i = e >> 5, j = e & 31;
            float v;
            if (i == j) v = p.db[0];
            else if (i < NP && j < NP) {
                int s = p.sp[(size_t)(g * NP + i) * NORI + g * NP + j];
                v = p.db[s < 100 ? s : 100];
            } else v = vb;
            p.Bg[(size_t)g * 1024 + e] = v;
        }
        return;
    }
    float* xs = (float*)smem;
    if (n < NORI && tid < NFEA) xs[tid] = p.x[(size_t)n * NFEA + tid];
    __syncthreads();
    int deg = p.degrees[n]; if (deg > 100) deg = 100;
    for (int d = tid; d < DIM; d += 256) {
        float v = p.cent_emb[(size_t)deg * DIM + d];
        if (n < NORI) {
            float acc = p.init_b[d];
            #pragma unroll
            for (int k = 0; k < NFEA; ++k) acc += xs[k] * p.init_W[(size_t)k * DIM + d];
            v += acc;
        }
        p.h[(size_t)n * DIM + d] = v;
    }
}

__device__ __forceinline__ void prep_qkv_unit(const MP& p, int tile, char* smem)
{
    if (tile >= 3072) {          // bias part
        int idx = (tile - 3072) * 256 + threadIdx.x;
        if (idx < NLAY * 1536) {
            int l = idx / 1536, c = idx % 1536;
            int which = c >> 9, cc = c & 511;
            const float* b = (which == 0) ? p.bq : (which == 1) ? p.bk : p.bv;
            p.bqkv[idx] = b[(size_t)l * 512 + cc];
        }
        return;
    }
    float (*tl)[33] = (float(*)[33])smem;
    int slice = tile >> 5;
    int tloc = tile & 31;
    int dt = tloc >> 1, kt = tloc & 1;
    int l = slice / 24; int rem = slice % 24; int which = rem >> 3; int hh = rem & 7;
    const float* W = (which == 0) ? p.Wq : (which == 1) ? p.Wk : p.Wv;
    const float* in = W + (size_t)(l * 8 + hh) * DIM * DKH;
    int tr = threadIdx.x >> 5, tc = threadIdx.x & 31;
    #pragma unroll
    for (int pp = 0; pp < 4; ++pp)
        tl[tr + pp * 8][tc] = in[(size_t)(dt * 32 + tr + pp * 8) * DKH + kt * 32 + tc];
    __syncthreads();
    unsigned short* out = p.Wqkv_t + ((size_t)l * 1536 + which * 512 + hh * 64 + kt * 32) * DIM + dt * 32;
    #pragma unroll
    for (int pp = 0; pp < 4; ++pp)
        out[(size_t)(tr + pp * 8) * DIM + tc] = f2bf(tl[tc][tr + pp * 8]);
}

__device__ __forceinline__ void prep_w_unit(const MP& p, int id, char* smem)
{
    float (*tl)[33] = (float(*)[33])smem;
    const float* in; unsigned short* outp; int R, C, l, rt, ct;
    if (id < 1024) {
        l = id >> 8; int t = id & 255; rt = t >> 4; ct = t & 15;
        in = p.Wo; outp = p.Wo_t; R = 512; C = 512;
    } else if (id < 5120) {
        int t2 = id - 1024; l = t2 >> 10; int t = t2 & 1023; rt = t >> 6; ct = t & 63;
        in = p.W1; outp = p.W1_t; R = 512; C = 2048;
    } else {
        int t2 = id - 5120; l = t2 >> 10; int t = t2 & 1023; rt = t >> 4; ct = t & 15;
        in = p.W2; outp = p.W2_t; R = 2048; C = 512;
    }
    const float* ip = in + (size_t)l * R * C;
    unsigned short* op = outp + (size_t)l * R * C;
    int r0 = rt * 32, c0 = ct * 32;
    int tr = threadIdx.x >> 5, tc = threadIdx.x & 31;
    #pragma unroll
    for (int pp = 0; pp < 4; ++pp)
        tl[tr + pp * 8][tc] = ip[(size_t)(r0 + tr + pp * 8) * C + c0 + tc];
    __syncthreads();
    #pragma unroll
    for (int pp = 0; pp < 4; ++pp)
        op[(size_t)(c0 + tr + pp * 8) * R + r0 + tc] = f2bf(tl[tc][tr + pp * 8]);
}

// ---------------------------------------------------------------- layernorm stage
__device__ void stage_ln(const MP& p, int row0, int nrows, bool docopy, char* smem)
{
    float* red = (float*)smem;
    int tid = threadIdx.x;
    int wave = tid >> 6;
    for (int r = blockIdx.x; r < nrows; r += GRID) {
        int n = row0 + r;
        const float* row = p.h + (size_t)n * DIM;
        float v0 = row[tid], v1 = row[tid + 256];
        float s = v0 + v1;
        float sq = v0 * v0 + v1 * v1;
        #pragma unroll
        for (int off = 32; off > 0; off >>= 1) {
            s  += __shfl_down(s, off);
            sq += __shfl_down(sq, off);
        }
        if ((tid & 63) == 0) { red[wave] = s; red[4 + wave] = sq; }
        __syncthreads();
        float ts  = red[0] + red[1] + red[2] + red[3];
        float tsq = red[4] + red[5] + red[6] + red[7];
        __syncthreads();                      // red reused next iteration
        float m   = ts * (1.0f / DIM);
        float var = tsq * (1.0f / DIM) - m * m;
        float inv = rsqrtf(var + 1e-5f);
        p.hn[(size_t)n * DIM + tid]       = f2bf((v0 - m) * inv);
        p.hn[(size_t)n * DIM + tid + 256] = f2bf((v1 - m) * inv);
        if (docopy) {                         // seed d_out with the residual h
            p.out[(size_t)(n - NORI) * DIM + tid]       = v0;
            p.out[(size_t)(n - NORI) * DIM + tid + 256] = v1;
        }
    }
}

// ---------------------------------------------------------------- gemm128 stage (m97 structure)
__device__ void stage_gemm128(const unsigned short* __restrict__ A,
    const unsigned short* __restrict__ Bt, const float* __restrict__ bias,
    void* __restrict__ out, int Nfull, int K, int flags, int P, int C,
    int SPLITK, char* smem)
{
    unsigned short* Asl = (unsigned short*)smem;
    unsigned short* Bsl = Asl + 128 * 64;
    int ntiles = P * C * SPLITK;
    int tid = threadIdx.x;
    int wave = tid >> 6, lane = tid & 63;
    int quad = lane >> 4, m16 = lane & 15;
    int mw = (wave >> 1) * 64, nw = (wave & 1) * 64;
    int lr = lane >> 3;
    int srcswz = ((lane & 7) ^ lr) << 3;
    int rdswz = (m16 & 7) << 4;
    int kslice = K / SPLITK;
    for (int id = blockIdx.x; id < ntiles; id += GRID) {
        int xcd = id & 7, t = id >> 3, Gp = P >> 3;
        int by = xcd + 8 * (t % Gp);
        int r2 = t / Gp;
        int bx = r2 % C;
        int bz = r2 / C;
        int row0 = by * 128, col0 = bx * 128;
        if ((flags & 4) && col0 < 512 && row0 + 128 <= NORI) continue;
        int kbeg = bz * kslice;
        const unsigned short* Abase = A + (size_t)row0 * K;
        const unsigned short* Bbase = Bt + (size_t)col0 * K;
        floatx4 acc[4][4] = {};
        __syncthreads();
        for (int k0 = kbeg; k0 < kbeg + kslice; k0 += 64) {
            #pragma unroll
            for (int pp = 0; pp < 4; ++pp) {
                int chunk = wave * 4 + pp;
                int r = chunk * 8 + lr;
                __builtin_amdgcn_global_load_lds(
                    (const __attribute__((address_space(1))) unsigned int*)
                        (Abase + (size_t)r * K + k0 + srcswz),
                    (__attribute__((address_space(3))) unsigned int*)
                        (Asl + chunk * 512 + lane * 8), 16, 0, 0);
                __builtin_amdgcn_global_load_lds(
                    (const __attribute__((address_space(1))) unsigned int*)
                        (Bbase + (size_t)r * K + k0 + srcswz),
                    (__attribute__((address_space(3))) unsigned int*)
                        (Bsl + chunk * 512 + lane * 8), 16, 0, 0);
            }
            __syncthreads();
            #pragma unroll
            for (int ks = 0; ks < 64; ks += 32) {
                short8 a[4], b[4];
                int cb = (ks + quad * 8) * 2;
                #pragma unroll
                for (int mi = 0; mi < 4; ++mi)
                    a[mi] = *(const short8*)((const char*)Asl +
                            (mw + mi * 16 + m16) * 128 + (cb ^ rdswz));
                #pragma unroll
                for (int ni = 0; ni < 4; ++ni)
                    b[ni] = *(const short8*)((const char*)Bsl +
                            (nw + ni * 16 + m16) * 128 + (cb ^ rdswz));
                #pragma unroll
                for (int mi = 0; mi < 4; ++mi)
                    #pragma unroll
                    for (int ni = 0; ni < 4; ++ni)
                        acc[mi][ni] = __builtin_amdgcn_mfma_f32_16x16x32_bf16(
                            a[mi], b[ni], acc[mi][ni], 0, 0, 0);
            }
            __syncthreads();
        }
        if (SPLITK == 1) {
            int do_relu = flags & 1, out_bf = flags & 2;
            #pragma unroll
            for (int mi = 0; mi < 4; ++mi) {
                #pragma unroll
                for (int ni = 0; ni < 4; ++ni) {
                    int col = col0 + nw + ni * 16 + m16;
                    float bval = bias[col];
                    #pragma unroll
                    for (int rr = 0; rr < 4; ++rr) {
                        int row = row0 + mw + mi * 16 + quad * 4 + rr;
                        float v = acc[mi][ni][rr] + bval;
                        if (do_relu) v = fmaxf(v, 0.0f);
                        if (out_bf) ((unsigned short*)out)[(size_t)row * Nfull + col] = f2bf(v);
                        else        ((float*)out)[(size_t)row * Nfull + col] = v;
                    }
                }
            }
        } else {
            float* ofp = (float*)out;
            float bscale = (bz == 0) ? 1.0f : 0.0f;
            #pragma unroll
            for (int mi = 0; mi < 4; ++mi) {
                #pragma unroll
                for (int ni = 0; ni < 4; ++ni) {
                    int col = col0 + nw + ni * 16 + m16;
                    float bval = bias[col] * bscale;
                    #pragma unroll
                    for (int rr = 0; rr < 4; ++rr) {
                        int row = row0 + mw + mi * 16 + quad * 4 + rr;
                        atomicAdd(&ofp[(size_t)row * Nfull + col], acc[mi][ni][rr] + bval);
                    }
                }
            }
        }
    }
}

// ---------------------------------------------------------------- gemm64 stage (small M)
__device__ void stage_gemm64(const unsigned short* __restrict__ A,
    const unsigned short* __restrict__ Bt, const float* __restrict__ bias,
    void* __restrict__ out, int Nfull, int K, int moff, int flags,
    int P, int C, int SPLITK, int orow, char* smem)
{
    unsigned short* Asl = (unsigned short*)smem;          // 64*72
    unsigned short* Bsl = Asl + 64 * 72;
    int ntiles = P * C * SPLITK;
    int tid = threadIdx.x;
    int wave = tid >> 6, lane = tid & 63;
    int quad = lane >> 4, m16 = lane & 15;
    int mw = (wave >> 1) * 32, nw = (wave & 1) * 32;
    int kslice = K / SPLITK;
    for (int id = blockIdx.x; id < ntiles; id += GRID) {
        int by, bx, bz;
        if (P >= 8) {
            int xcd = id & 7, t = id >> 3, Gp = P >> 3;
            by = xcd + 8 * (t % Gp);
            int r2 = t / Gp;
            bx = r2 % C;
            bz = r2 / C;
        } else {
            by = id % P; int r2 = id / P; bx = r2 % C; bz = r2 / C;
        }
        int row0 = moff + by * 64, col0 = bx * 64;
        if ((flags & 4) && col0 < 512 && row0 < NORI) continue;
        int kbeg = bz * kslice;
        floatx4 acc[2][2] = {};
        __syncthreads();
        for (int k0 = kbeg; k0 < kbeg + kslice; k0 += 64) {
            #pragma unroll
            for (int pp = 0; pp < 2; ++pp) {
                int idx = (pp * 256 + tid) * 8;
                int r = idx >> 6, kk = idx & 63;
                *(float4*)(Asl + r * 72 + kk) =
                    *(const float4*)(A + (size_t)(row0 + r) * K + k0 + kk);
                *(float4*)(Bsl + r * 72 + kk) =
                    *(const float4*)(Bt + (size_t)(col0 + r) * K + k0 + kk);
            }
            __syncthreads();
            #pragma unroll
            for (int ks = 0; ks < 64; ks += 32) {
                short8 a[2], b[2];
                #pragma unroll
                for (int mi = 0; mi < 2; ++mi)
                    a[mi] = *(const short8*)(Asl + (mw + mi * 16 + m16) * 72 + ks + quad * 8);
                #pragma unroll
                for (int ni = 0; ni < 2; ++ni)
                    b[ni] = *(const short8*)(Bsl + (nw + ni * 16 + m16) * 72 + ks + quad * 8);
                #pragma unroll
                for (int mi = 0; mi < 2; ++mi)
                    #pragma unroll
                    for (int ni = 0; ni < 2; ++ni)
                        acc[mi][ni] = __builtin_amdgcn_mfma_f32_16x16x32_bf16(
                            a[mi], b[ni], acc[mi][ni], 0, 0, 0);
            }
            __syncthreads();
        }
        if (SPLITK == 1) {
            int do_relu = flags & 1, out_bf = flags & 2;
            #pragma unroll
            for (int mi = 0; mi < 2; ++mi) {
                #pragma unroll
                for (int ni = 0; ni < 2; ++ni) {
                    int col = col0 + nw + ni * 16 + m16;
                    float bval = bias[col];
                    #pragma unroll
                    for (int rr = 0; rr < 4; ++rr) {
                        int row = row0 + mw + mi * 16 + quad * 4 + rr;
                        float v = acc[mi][ni][rr] + bval;
                        if (do_relu) v = fmaxf(v, 0.0f);
                        if (out_bf) ((unsigned short*)out)[(size_t)(row - orow) * Nfull + col] = f2bf(v);
                        else        ((float*)out)[(size_t)(row - orow) * Nfull + col] = v;
                    }
                }
            }
        } else {
            float* ofp = (float*)out;
            float bscale = (bz == 0) ? 1.0f : 0.0f;
            #pragma unroll
            for (int mi = 0; mi < 2; ++mi) {
                #pragma unroll
                for (int ni = 0; ni < 2; ++ni) {
                    int col = col0 + nw + ni * 16 + m16;
                    float bval = bias[col] * bscale;
                    #pragma unroll
                    for (int rr = 0; rr < 4; ++rr) {
                        int row = row0 + mw + mi * 16 + quad * 4 + rr;
                        atomicAdd(&ofp[(size_t)(row - orow) * Nfull + col],
                                  acc[mi][ni][rr] + bval);
                    }
                }
            }
        }
    }
}

// ---------------------------------------------------------------- attention stage (layers 0..2)
__device__ void stage_attn(const MP& p, char* smem)
{
    float (*Qs)[65] = (float(*)[65])(smem);
    float (*Ks)[65] = (float(*)[65])(smem + 8320);
    float (*Vs)[65] = (float(*)[65])(smem + 16640);
    float (*S)[33]  = (float(*)[33])(smem + 24960);
    int tid = threadIdx.x;
    int i = tid >> 3;
    int c0 = (tid & 7) * 8;
    for (int u = blockIdx.x; u < NG * NHD; u += GRID) {
        int g = u >> 3, hh = u & 7;
        __syncthreads();
        int gn = (i < NP) ? g * NP + i : NORI + g;
        const unsigned short* base = p.qkv + (size_t)gn * 1536 + hh * DKH;
        short8 qv = *(const short8*)(base + c0);
        short8 kv = *(const short8*)(base + 512 + c0);
        short8 vv = *(const short8*)(base + 1024 + c0);
        #pragma unroll
        for (int j = 0; j < 8; ++j) {
            Qs[i][c0 + j] = bf2f((unsigned short)qv[j]);
            Ks[i][c0 + j] = bf2f((unsigned short)kv[j]);
            Vs[i][c0 + j] = bf2f((unsigned short)vv[j]);
        }
        __syncthreads();
        const float scale = 0.125f;
        #pragma unroll
        for (int e = 0; e < 4; ++e) {
            int idx = tid + e * 256;
            int si = idx >> 5, sj = idx & 31;
            float dot = 0.0f;
            #pragma unroll
            for (int k = 0; k < DKH; ++k) dot += Qs[si][k] * Ks[sj][k];
            S[si][sj] = dot * scale + p.Bg[(size_t)g * 1024 + si * 32 + sj];
        }
        __syncthreads();
        if (tid < 32) {
            float mx = -1e30f;
            #pragma unroll
            for (int j = 0; j < 32; ++j) mx = fmaxf(mx, S[tid][j]);
            float sum = 0.0f;
            #pragma unroll
            for (int j = 0; j < 32; ++j) { float e = __expf(S[tid][j] - mx); S[tid][j] = e; sum += e; }
            float inv = 1.0f / sum;
            #pragma unroll
            for (int j = 0; j < 32; ++j) S[tid][j] *= inv;
        }
        __syncthreads();
        short8 ov;
        #pragma unroll
        for (int cc = 0; cc < 8; ++cc) {
            float acc = 0.0f;
            #pragma unroll
            for (int j = 0; j < 32; ++j) acc += S[i][j] * Vs[j][c0 + cc];
            ov[cc] = (short)f2bf(acc);
        }
        *(short8*)(p.o + (size_t)gn * DIM + hh * DKH + c0) = ov;
        __syncthreads();
    }
}

// ---------------------------------------------------------------- last-layer attention (256 thr)
__device__ void stage_attn_last(const MP& p, char* smem)
{
    float (*Ks)[65] = (float(*)[65])(smem);
    float (*Vs)[65] = (float(*)[65])(smem + 8320);
    float* Qs = (float*)(smem + 16640);     // 64
    float* Pp = Qs + 64;                    // 32
    int tid = threadIdx.x;
    int j = tid >> 3;
    int c0 = (tid & 7) * 8;
    for (int u = blockIdx.x; u < NG * NHD; u += GRID) {
        int g = u >> 3, hh = u & 7;
        __syncthreads();
        int gn = (j < NP) ? g * NP + j : NORI + g;
        const unsigned short* kb = p.qkv + (size_t)gn * 1536 + hh * DKH;
        short8 k8 = *(const short8*)(kb + 512 + c0);
        short8 v8 = *(const short8*)(kb + 1024 + c0);
        #pragma unroll
        for (int t = 0; t < 8; ++t) {
            Ks[j][c0 + t] = bf2f((unsigned short)k8[t]);
            Vs[j][c0 + t] = bf2f((unsigned short)v8[t]);
        }
        if (tid < 64) Qs[tid] = bf2f(p.qkv[(size_t)(NORI + g) * 1536 + hh * DKH + tid]);
        __syncthreads();
        if (tid < 64) {
            float s;
            if (tid < 32) {
                float dot = 0.0f;
                #pragma unroll
                for (int k = 0; k < 64; ++k) dot += Qs[k] * Ks[tid][k];
                s = dot * 0.125f + p.Bg[(size_t)g * 1024 + 31 * 32 + tid];
            } else s = -1e30f;
            float mx = s;
            #pragma unroll
            for (int off = 32; off > 0; off >>= 1) mx = fmaxf(mx, __shfl_xor(mx, off));
            float e = (tid < 32) ? __expf(s - mx) : 0.0f;
            float sum = e;
            #pragma unroll
            for (int off = 32; off > 0; off >>= 1) sum += __shfl_xor(sum, off);
            if (tid < 32) Pp[tid] = e / sum;
        }
        __syncthreads();
        if (tid < 64) {
            float acc = 0.0f;
            #pragma unroll
            for (int jj = 0; jj < 32; ++jj) acc += Pp[jj] * Vs[jj][tid];
            p.o[(size_t)(NORI + g) * DIM + hh * DKH + tid] = f2bf(acc);
        }
        __syncthreads();
    }
}

// ---------------------------------------------------------------- mega kernel
__global__ __launch_bounds__(256, 4) void mega(MP p)
{
    __shared__ __align__(16) char smem[32768];
    unsigned ep = 0;

    // stage 0: prep (init_h+B, QKV weight transpose, Wo/W1/W2 transpose)
    for (int u = blockIdx.x; u < 2112 + 3096 + 9216; u += GRID) {
        __syncthreads();
        if (u < 2112)      prep_inith_unit(p, u, smem);
        else if (u < 5208) prep_qkv_unit(p, u - 2112, smem);
        else               prep_w_unit(p, u - 5208, smem);
    }
    gbar(p.bar, ++ep);

    for (int l = 0; l < NLAY; ++l) {
        const bool last = (l == NLAY - 1);
        stage_ln(p, 0, NT, false, smem);
        gbar(p.bar, ++ep);
        stage_gemm128(p.hn, p.Wqkv_t + (size_t)l * 1536 * DIM, p.bqkv + l * 1536,
                      p.qkv, 1536, DIM, last ? 6 : 2, 16, 12, 1, smem);
        gbar(p.bar, ++ep);
        if (!last) stage_attn(p, smem);
        else       stage_attn_last(p, smem);
        gbar(p.bar, ++ep);
        if (!last)
            stage_gemm128(p.o, p.Wo_t + (size_t)l * DIM * DIM, p.bo + l * DIM,
                          p.h, DIM, DIM, 0, 16, 4, 4, smem);
        else
            stage_gemm64(p.o, p.Wo_t + (size_t)l * DIM * DIM, p.bo + l * DIM,
                         p.h, DIM, DIM, NORI, 0, 1, 8, 8, 0, smem);
        gbar(p.bar, ++ep);
        stage_ln(p, last ? NORI : 0, last ? NG : NT, last, smem);
        gbar(p.bar, ++ep);
        if (!last)
            stage_gemm128(p.hn, p.W1_t + (size_t)l * FFD * DIM, p.b1 + l * FFD,
                          p.qkv, FFD, DIM, 3, 16, 16, 1, smem);
        else
            stage_gemm64(p.hn, p.W1_t + (size_t)l * FFD * DIM, p.b1 + l * FFD,
                         p.qkv, FFD, DIM, NORI, 3, 1, 32, 1, 0, smem);
        gbar(p.bar, ++ep);
        if (!last)
            stage_gemm128(p.qkv, p.W2_t + (size_t)l * DIM * FFD, p.b2 + l * DIM,
                          p.h, DIM, FFD, 0, 16, 4, 4, smem);
        else
            stage_gemm64(p.qkv, p.W2_t + (size_t)l * DIM * FFD, p.b2 + l * DIM,
                         p.out, DIM, FFD, NORI, 0, 1, 8, 8, NORI, smem);
        if (!last) gbar(p.bar, ++ep);
    }
}

// ---------------------------------------------------------------- launch
extern "C" void kernel_launch(void* const* d_in, const int* in_sizes, int n_in,
                              void* d_out, int out_size, void* d_ws, size_t ws_size,
                              hipStream_t stream)
{
    MP p;
    p.x        = (const float*)d_in[0];
    p.sp       = (const int*)d_in[1];
    p.degrees  = (const int*)d_in[3];
    p.init_W   = (const float*)d_in[4];
    p.init_b   = (const float*)d_in[5];
    p.cent_emb = (const float*)d_in[6];
    p.db       = (const float*)d_in[7];
    p.vbias    = (const float*)d_in[8];
    p.Wq       = (const float*)d_in[9];
    p.bq       = (const float*)d_in[10];
    p.Wk       = (const float*)d_in[11];
    p.bk       = (const float*)d_in[12];
    p.Wv       = (const float*)d_in[13];
    p.bv       = (const float*)d_in[14];
    p.Wo       = (const float*)d_in[15];
    p.bo       = (const float*)d_in[16];
    p.W1       = (const float*)d_in[17];
    p.b1       = (const float*)d_in[18];
    p.W2       = (const float*)d_in[19];
    p.b2       = (const float*)d_in[20];

    char* ws = (char*)d_ws;
    p.h      = (float*)ws;          ws += (size_t)NT * DIM * 4;
    p.hn     = (unsigned short*)ws; ws += (size_t)NT * DIM * 2;
    p.o      = (unsigned short*)ws; ws += (size_t)NT * DIM * 2;
    p.qkv    = (unsigned short*)ws; ws += (size_t)NT * FFD * 2;      // aliased qkv/ffn
    p.Bg     = (float*)ws;          ws += (size_t)NG * 1024 * 4;
    p.Wqkv_t = (unsigned short*)ws; ws += (size_t)NLAY * 1536 * DIM * 2;
    p.Wo_t   = (unsigned short*)ws; ws += (size_t)NLAY * DIM * DIM * 2;
    p.W1_t   = (unsigned short*)ws; ws += (size_t)NLAY * FFD * DIM * 2;
    p.W2_t   = (unsigned short*)ws; ws += (size_t)NLAY * DIM * FFD * 2;
    p.bqkv   = (float*)ws;          ws += (size_t)NLAY * 1536 * 4;
    p.bar    = (unsigned*)ws;       ws += 16384;
    p.out    = (float*)d_out;

    bar_init<<<1, 256, 0, stream>>>(p.bar);
    mega<<<GRID, 256, 0, stream>>>(p);
}

// Round 7
// 843.013 us; speedup vs baseline: 1.9626x; 1.9626x over previous
//
#include <hip/hip_runtime.h>

// Graphormer encoder — single persistent mega-kernel, hierarchical grid barrier.
// R15 = R14 resubmitted (previous round died to container-acquisition infra
// failure; no kernel data). Config: __launch_bounds__(256,2) (proven no-spill,
// VGPR=128) with GRID=512 (2 blocks/CU, empirically resident in R11).
// R12's relaxed-poll monotonic barrier, 16 groups x 32 blocks.

#define NG   64
#define NP   31
#define NORI 1984
#define NT   2048
#define DIM  512
#define NHD  8
#define DKH  64
#define FFD  2048
#define NLAY 4
#define NFEA 32
#define GRID 512
#define GSH  5          // 32 blocks/group -> 16 groups

typedef __attribute__((ext_vector_type(8))) short short8;
typedef __attribute__((ext_vector_type(4))) float floatx4;

__device__ __forceinline__ unsigned short f2bf(float f) {
    union { float f; unsigned u; } v; v.f = f;
    unsigned r = v.u + 0x7fffu + ((v.u >> 16) & 1u);
    return (unsigned short)(r >> 16);
}
__device__ __forceinline__ float bf2f(unsigned short u) {
    union { unsigned u; float f; } v; v.u = ((unsigned)u) << 16;
    return v.f;
}

struct MP {
    const float* x; const int* sp; const int* degrees;
    const float* init_W; const float* init_b; const float* cent_emb;
    const float* db; const float* vbias;
    const float* Wq; const float* Wk; const float* Wv;
    const float* bq; const float* bk; const float* bv;
    const float* Wo; const float* bo; const float* W1; const float* b1;
    const float* W2; const float* b2;
    float* h; unsigned short* hn; unsigned short* o; unsigned short* qkv;
    float* Bg;
    unsigned short* Wqkv_t; unsigned short* Wo_t; unsigned short* W1_t; unsigned short* W2_t;
    float* bqkv;
    unsigned* bar;
    float* out;
};

// ---------------------------------------------------------------- grid barrier
// Monotonic 2-level counters. Group g (16 groups): cnt=bar[g*64], gen=bar[g*64+32].
// Root: cnt=bar[2048], gen=bar[2080]. Epoch e: leaf target e*32, root target e*16.
__device__ __forceinline__ void gbar(unsigned* bar, unsigned e)
{
    __syncthreads();
    if (threadIdx.x == 0) {
        __builtin_amdgcn_fence(__ATOMIC_RELEASE, "agent");      // writeback
        int g = blockIdx.x >> GSH;
        unsigned* leafc = bar + g * 64;
        unsigned* leafg = bar + g * 64 + 32;
        unsigned* rootc = bar + 2048;
        unsigned* rootg = bar + 2080;
        unsigned t = __hip_atomic_fetch_add(leafc, 1u, __ATOMIC_RELAXED,
                                            __HIP_MEMORY_SCOPE_AGENT) + 1u;
        if (t == (e << GSH)) {                     // last of 32 in group
            unsigned r = __hip_atomic_fetch_add(rootc, 1u, __ATOMIC_RELAXED,
                                                __HIP_MEMORY_SCOPE_AGENT) + 1u;
            if (r == (e << 4)) {                   // last of 16 groups
                __hip_atomic_fetch_add(rootg, 1u, __ATOMIC_RELAXED,
                                       __HIP_MEMORY_SCOPE_AGENT);
            } else {
                while (__hip_atomic_load(rootg, __ATOMIC_RELAXED,
                                         __HIP_MEMORY_SCOPE_AGENT) < e)
                    __builtin_amdgcn_s_sleep(1);
            }
            __hip_atomic_fetch_add(leafg, 1u, __ATOMIC_RELAXED,
                                   __HIP_MEMORY_SCOPE_AGENT);
        } else {
            while (__hip_atomic_load(leafg, __ATOMIC_RELAXED,
                                     __HIP_MEMORY_SCOPE_AGENT) < e)
                __builtin_amdgcn_s_sleep(1);
        }
        __builtin_amdgcn_fence(__ATOMIC_ACQUIRE, "agent");      // invalidate
    }
    __syncthreads();
}

__global__ void bar_init(unsigned* bar) {
    for (int i = threadIdx.x; i < 4096; i += 256) bar[i] = 0u;
}

// ---------------------------------------------------------------- prep units
__device__ __forceinline__ void prep_inith_unit(const MP& p, int n, char* smem)
{
    int tid = threadIdx.x;
    if (n >= NT) {               // build_B: one unit per graph
        int g = n - NT;
        float vb = p.vbias[0];
        for (int e = tid; e < 1024; e += 256) {
            int i = e >> 5, j = e & 31;
            float v;
            if (i == j) v = p.db[0];
            else if (i < NP && j < NP) {
                int s = p.sp[(size_t)(g * NP + i) * NORI + g * NP + j];
                v = p.db[s < 100 ? s : 100];
            } else v = vb;
            p.Bg[(size_t)g * 1024 + e] = v;
        }
        return;
    }
    float* xs = (float*)smem;
    if (n < NORI && tid < NFEA) xs[tid] = p.x[(size_t)n * NFEA + tid];
    __syncthreads();
    int deg = p.degrees[n]; if (deg > 100) deg = 100;
    for (int d = tid; d < DIM; d += 256) {
        float v = p.cent_emb[(size_t)deg * DIM + d];
        if (n < NORI) {
            float acc = p.init_b[d];
            #pragma unroll
            for (int k = 0; k < NFEA; ++k) acc += xs[k] * p.init_W[(size_t)k * DIM + d];
            v += acc;
        }
        p.h[(size_t)n * DIM + d] = v;
    }
}

__device__ __forceinline__ void prep_qkv_unit(const MP& p, int tile, char* smem)
{
    if (tile >= 3072) {          // bias part
        int idx = (tile - 3072) * 256 + threadIdx.x;
        if (idx < NLAY * 1536) {
            int l = idx / 1536, c = idx % 1536;
            int which = c >> 9, cc = c & 511;
            const float* b = (which == 0) ? p.bq : (which == 1) ? p.bk : p.bv;
            p.bqkv[idx] = b[(size_t)l * 512 + cc];
        }
        return;
    }
    float (*tl)[33] = (float(*)[33])smem;
    int slice = tile >> 5;
    int tloc = tile & 31;
    int dt = tloc >> 1, kt = tloc & 1;
    int l = slice / 24; int rem = slice % 24; int which = rem >> 3; int hh = rem & 7;
    const float* W = (which == 0) ? p.Wq : (which == 1) ? p.Wk : p.Wv;
    const float* in = W + (size_t)(l * 8 + hh) * DIM * DKH;
    int tr = threadIdx.x >> 5, tc = threadIdx.x & 31;
    #pragma unroll
    for (int pp = 0; pp < 4; ++pp)
        tl[tr + pp * 8][tc] = in[(size_t)(dt * 32 + tr + pp * 8) * DKH + kt * 32 + tc];
    __syncthreads();
    unsigned short* out = p.Wqkv_t + ((size_t)l * 1536 + which * 512 + hh * 64 + kt * 32) * DIM + dt * 32;
    #pragma unroll
    for (int pp = 0; pp < 4; ++pp)
        out[(size_t)(tr + pp * 8) * DIM + tc] = f2bf(tl[tc][tr + pp * 8]);
}

__device__ __forceinline__ void prep_w_unit(const MP& p, int id, char* smem)
{
    float (*tl)[33] = (float(*)[33])smem;
    const float* in; unsigned short* outp; int R, C, l, rt, ct;
    if (id < 1024) {
        l = id >> 8; int t = id & 255; rt = t >> 4; ct = t & 15;
        in = p.Wo; outp = p.Wo_t; R = 512; C = 512;
    } else if (id < 5120) {
        int t2 = id - 1024; l = t2 >> 10; int t = t2 & 1023; rt = t >> 6; ct = t & 63;
        in = p.W1; outp = p.W1_t; R = 512; C = 2048;
    } else {
        int t2 = id - 5120; l = t2 >> 10; int t = t2 & 1023; rt = t >> 4; ct = t & 15;
        in = p.W2; outp = p.W2_t; R = 2048; C = 512;
    }
    const float* ip = in + (size_t)l * R * C;
    unsigned short* op = outp + (size_t)l * R * C;
    int r0 = rt * 32, c0 = ct * 32;
    int tr = threadIdx.x >> 5, tc = threadIdx.x & 31;
    #pragma unroll
    for (int pp = 0; pp < 4; ++pp)
        tl[tr + pp * 8][tc] = ip[(size_t)(r0 + tr + pp * 8) * C + c0 + tc];
    __syncthreads();
    #pragma unroll
    for (int pp = 0; pp < 4; ++pp)
        op[(size_t)(c0 + tr + pp * 8) * R + r0 + tc] = f2bf(tl[tc][tr + pp * 8]);
}

// ---------------------------------------------------------------- layernorm stage
__device__ void stage_ln(const MP& p, int row0, int nrows, bool docopy, char* smem)
{
    float* red = (float*)smem;
    int tid = threadIdx.x;
    int wave = tid >> 6;
    for (int r = blockIdx.x; r < nrows; r += GRID) {
        int n = row0 + r;
        const float* row = p.h + (size_t)n * DIM;
        float v0 = row[tid], v1 = row[tid + 256];
        float s = v0 + v1;
        float sq = v0 * v0 + v1 * v1;
        #pragma unroll
        for (int off = 32; off > 0; off >>= 1) {
            s  += __shfl_down(s, off);
            sq += __shfl_down(sq, off);
        }
        if ((tid & 63) == 0) { red[wave] = s; red[4 + wave] = sq; }
        __syncthreads();
        float ts  = red[0] + red[1] + red[2] + red[3];
        float tsq = red[4] + red[5] + red[6] + red[7];
        __syncthreads();                      // red reused next iteration
        float m   = ts * (1.0f / DIM);
        float var = tsq * (1.0f / DIM) - m * m;
        float inv = rsqrtf(var + 1e-5f);
        p.hn[(size_t)n * DIM + tid]       = f2bf((v0 - m) * inv);
        p.hn[(size_t)n * DIM + tid + 256] = f2bf((v1 - m) * inv);
        if (docopy) {                         // seed d_out with the residual h
            p.out[(size_t)(n - NORI) * DIM + tid]       = v0;
            p.out[(size_t)(n - NORI) * DIM + tid + 256] = v1;
        }
    }
}

// ---------------------------------------------------------------- gemm128 stage (m97 structure)
__device__ void stage_gemm128(const unsigned short* __restrict__ A,
    const unsigned short* __restrict__ Bt, const float* __restrict__ bias,
    void* __restrict__ out, int Nfull, int K, int flags, int P, int C,
    int SPLITK, char* smem)
{
    unsigned short* Asl = (unsigned short*)smem;
    unsigned short* Bsl = Asl + 128 * 64;
    int ntiles = P * C * SPLITK;
    int tid = threadIdx.x;
    int wave = tid >> 6, lane = tid & 63;
    int quad = lane >> 4, m16 = lane & 15;
    int mw = (wave >> 1) * 64, nw = (wave & 1) * 64;
    int lr = lane >> 3;
    int srcswz = ((lane & 7) ^ lr) << 3;
    int rdswz = (m16 & 7) << 4;
    int kslice = K / SPLITK;
    for (int id = blockIdx.x; id < ntiles; id += GRID) {
        int xcd = id & 7, t = id >> 3, Gp = P >> 3;
        int by = xcd + 8 * (t % Gp);
        int r2 = t / Gp;
        int bx = r2 % C;
        int bz = r2 / C;
        int row0 = by * 128, col0 = bx * 128;
        if ((flags & 4) && col0 < 512 && row0 + 128 <= NORI) continue;
        int kbeg = bz * kslice;
        const unsigned short* Abase = A + (size_t)row0 * K;
        const unsigned short* Bbase = Bt + (size_t)col0 * K;
        floatx4 acc[4][4] = {};
        __syncthreads();
        for (int k0 = kbeg; k0 < kbeg + kslice; k0 += 64) {
            #pragma unroll
            for (int pp = 0; pp < 4; ++pp) {
                int chunk = wave * 4 + pp;
                int r = chunk * 8 + lr;
                __builtin_amdgcn_global_load_lds(
                    (const __attribute__((address_space(1))) unsigned int*)
                        (Abase + (size_t)r * K + k0 + srcswz),
                    (__attribute__((address_space(3))) unsigned int*)
                        (Asl + chunk * 512 + lane * 8), 16, 0, 0);
                __builtin_amdgcn_global_load_lds(
                    (const __attribute__((address_space(1))) unsigned int*)
                        (Bbase + (size_t)r * K + k0 + srcswz),
                    (__attribute__((address_space(3))) unsigned int*)
                        (Bsl + chunk * 512 + lane * 8), 16, 0, 0);
            }
            __syncthreads();
            #pragma unroll
            for (int ks = 0; ks < 64; ks += 32) {
                short8 a[4], b[4];
                int cb = (ks + quad * 8) * 2;
                #pragma unroll
                for (int mi = 0; mi < 4; ++mi)
                    a[mi] = *(const short8*)((const char*)Asl +
                            (mw + mi * 16 + m16) * 128 + (cb ^ rdswz));
                #pragma unroll
                for (int ni = 0; ni < 4; ++ni)
                    b[ni] = *(const short8*)((const char*)Bsl +
                            (nw + ni * 16 + m16) * 128 + (cb ^ rdswz));
                #pragma unroll
                for (int mi = 0; mi < 4; ++mi)
                    #pragma unroll
                    for (int ni = 0; ni < 4; ++ni)
                        acc[mi][ni] = __builtin_amdgcn_mfma_f32_16x16x32_bf16(
                            a[mi], b[ni], acc[mi][ni], 0, 0, 0);
            }
            __syncthreads();
        }
        if (SPLITK == 1) {
            int do_relu = flags & 1, out_bf = flags & 2;
            #pragma unroll
            for (int mi = 0; mi < 4; ++mi) {
                #pragma unroll
                for (int ni = 0; ni < 4; ++ni) {
                    int col = col0 + nw + ni * 16 + m16;
                    float bval = bias[col];
                    #pragma unroll
                    for (int rr = 0; rr < 4; ++rr) {
                        int row = row0 + mw + mi * 16 + quad * 4 + rr;
                        float v = acc[mi][ni][rr] + bval;
                        if (do_relu) v = fmaxf(v, 0.0f);
                        if (out_bf) ((unsigned short*)out)[(size_t)row * Nfull + col] = f2bf(v);
                        else        ((float*)out)[(size_t)row * Nfull + col] = v;
                    }
                }
            }
        } else {
            float* ofp = (float*)out;
            float bscale = (bz == 0) ? 1.0f : 0.0f;
            #pragma unroll
            for (int mi = 0; mi < 4; ++mi) {
                #pragma unroll
                for (int ni = 0; ni < 4; ++ni) {
                    int col = col0 + nw + ni * 16 + m16;
                    float bval = bias[col] * bscale;
                    #pragma unroll
                    for (int rr = 0; rr < 4; ++rr) {
                        int row = row0 + mw + mi * 16 + quad * 4 + rr;
                        atomicAdd(&ofp[(size_t)row * Nfull + col], acc[mi][ni][rr] + bval);
                    }
                }
            }
        }
    }
}

// ---------------------------------------------------------------- gemm64 stage (small M)
__device__ void stage_gemm64(const unsigned short* __restrict__ A,
    const unsigned short* __restrict__ Bt, const float* __restrict__ bias,
    void* __restrict__ out, int Nfull, int K, int moff, int flags,
    int P, int C, int SPLITK, int orow, char* smem)
{
    unsigned short* Asl = (unsigned short*)smem;          // 64*72
    unsigned short* Bsl = Asl + 64 * 72;
    int ntiles = P * C * SPLITK;
    int tid = threadIdx.x;
    int wave = tid >> 6, lane = tid & 63;
    int quad = lane >> 4, m16 = lane & 15;
    int mw = (wave >> 1) * 32, nw = (wave & 1) * 32;
    int kslice = K / SPLITK;
    for (int id = blockIdx.x; id < ntiles; id += GRID) {
        int by, bx, bz;
        if (P >= 8) {
            int xcd = id & 7, t = id >> 3, Gp = P >> 3;
            by = xcd + 8 * (t % Gp);
            int r2 = t / Gp;
            bx = r2 % C;
            bz = r2 / C;
        } else {
            by = id % P; int r2 = id / P; bx = r2 % C; bz = r2 / C;
        }
        int row0 = moff + by * 64, col0 = bx * 64;
        if ((flags & 4) && col0 < 512 && row0 < NORI) continue;
        int kbeg = bz * kslice;
        floatx4 acc[2][2] = {};
        __syncthreads();
        for (int k0 = kbeg; k0 < kbeg + kslice; k0 += 64) {
            #pragma unroll
            for (int pp = 0; pp < 2; ++pp) {
                int idx = (pp * 256 + tid) * 8;
                int r = idx >> 6, kk = idx & 63;
                *(float4*)(Asl + r * 72 + kk) =
                    *(const float4*)(A + (size_t)(row0 + r) * K + k0 + kk);
                *(float4*)(Bsl + r * 72 + kk) =
                    *(const float4*)(Bt + (size_t)(col0 + r) * K + k0 + kk);
            }
            __syncthreads();
            #pragma unroll
            for (int ks = 0; ks < 64; ks += 32) {
                short8 a[2], b[2];
                #pragma unroll
                for (int mi = 0; mi < 2; ++mi)
                    a[mi] = *(const short8*)(Asl + (mw + mi * 16 + m16) * 72 + ks + quad * 8);
                #pragma unroll
                for (int ni = 0; ni < 2; ++ni)
                    b[ni] = *(const short8*)(Bsl + (nw + ni * 16 + m16) * 72 + ks + quad * 8);
                #pragma unroll
                for (int mi = 0; mi < 2; ++mi)
                    #pragma unroll
                    for (int ni = 0; ni < 2; ++ni)
                        acc[mi][ni] = __builtin_amdgcn_mfma_f32_16x16x32_bf16(
                            a[mi], b[ni], acc[mi][ni], 0, 0, 0);
            }
            __syncthreads();
        }
        if (SPLITK == 1) {
            int do_relu = flags & 1, out_bf = flags & 2;
            #pragma unroll
            for (int mi = 0; mi < 2; ++mi) {
                #pragma unroll
                for (int ni = 0; ni < 2; ++ni) {
                    int col = col0 + nw + ni * 16 + m16;
                    float bval = bias[col];
                    #pragma unroll
                    for (int rr = 0; rr < 4; ++rr) {
                        int row = row0 + mw + mi * 16 + quad * 4 + rr;
                        float v = acc[mi][ni][rr] + bval;
                        if (do_relu) v = fmaxf(v, 0.0f);
                        if (out_bf) ((unsigned short*)out)[(size_t)(row - orow) * Nfull + col] = f2bf(v);
                        else        ((float*)out)[(size_t)(row - orow) * Nfull + col] = v;
                    }
                }
            }
        } else {
            float* ofp = (float*)out;
            float bscale = (bz == 0) ? 1.0f : 0.0f;
            #pragma unroll
            for (int mi = 0; mi < 2; ++mi) {
                #pragma unroll
                for (int ni = 0; ni < 2; ++ni) {
                    int col = col0 + nw + ni * 16 + m16;
                    float bval = bias[col] * bscale;
                    #pragma unroll
                    for (int rr = 0; rr < 4; ++rr) {
                        int row = row0 + mw + mi * 16 + quad * 4 + rr;
                        atomicAdd(&ofp[(size_t)(row - orow) * Nfull + col],
                                  acc[mi][ni][rr] + bval);
                    }
                }
            }
        }
    }
}

// ---------------------------------------------------------------- attention stage (layers 0..2)
__device__ void stage_attn(const MP& p, char* smem)
{
    float (*Qs)[65] = (float(*)[65])(smem);
    float (*Ks)[65] = (float(*)[65])(smem + 8320);
    float (*Vs)[65] = (float(*)[65])(smem + 16640);
    float (*S)[33]  = (float(*)[33])(smem + 24960);
    int tid = threadIdx.x;
    int i = tid >> 3;
    int c0 = (tid & 7) * 8;
    for (int u = blockIdx.x; u < NG * NHD; u += GRID) {
        int g = u >> 3, hh = u & 7;
        __syncthreads();
        int gn = (i < NP) ? g * NP + i : NORI + g;
        const unsigned short* base = p.qkv + (size_t)gn * 1536 + hh * DKH;
        short8 qv = *(const short8*)(base + c0);
        short8 kv = *(const short8*)(base + 512 + c0);
        short8 vv = *(const short8*)(base + 1024 + c0);
        #pragma unroll
        for (int j = 0; j < 8; ++j) {
            Qs[i][c0 + j] = bf2f((unsigned short)qv[j]);
            Ks[i][c0 + j] = bf2f((unsigned short)kv[j]);
            Vs[i][c0 + j] = bf2f((unsigned short)vv[j]);
        }
        __syncthreads();
        const float scale = 0.125f;
        #pragma unroll
        for (int e = 0; e < 4; ++e) {
            int idx = tid + e * 256;
            int si = idx >> 5, sj = idx & 31;
            float dot = 0.0f;
            #pragma unroll
            for (int k = 0; k < DKH; ++k) dot += Qs[si][k] * Ks[sj][k];
            S[si][sj] = dot * scale + p.Bg[(size_t)g * 1024 + si * 32 + sj];
        }
        __syncthreads();
        if (tid < 32) {
            float mx = -1e30f;
            #pragma unroll
            for (int j = 0; j < 32; ++j) mx = fmaxf(mx, S[tid][j]);
            float sum = 0.0f;
            #pragma unroll
            for (int j = 0; j < 32; ++j) { float e = __expf(S[tid][j] - mx); S[tid][j] = e; sum += e; }
            float inv = 1.0f / sum;
            #pragma unroll
            for (int j = 0; j < 32; ++j) S[tid][j] *= inv;
        }
        __syncthreads();
        short8 ov;
        #pragma unroll
        for (int cc = 0; cc < 8; ++cc) {
            float acc = 0.0f;
            #pragma unroll
            for (int j = 0; j < 32; ++j) acc += S[i][j] * Vs[j][c0 + cc];
            ov[cc] = (short)f2bf(acc);
        }
        *(short8*)(p.o + (size_t)gn * DIM + hh * DKH + c0) = ov;
        __syncthreads();
    }
}

// ---------------------------------------------------------------- last-layer attention (256 thr)
__device__ void stage_attn_last(const MP& p, char* smem)
{
    float (*Ks)[65] = (float(*)[65])(smem);
    float (*Vs)[65] = (float(*)[65])(smem + 8320);
    float* Qs = (float*)(smem + 16640);     // 64
    float* Pp = Qs + 64;                    // 32
    int tid = threadIdx.x;
    int j = tid >> 3;
    int c0 = (tid & 7) * 8;
    for (int u = blockIdx.x; u < NG * NHD; u += GRID) {
        int g = u >> 3, hh = u & 7;
        __syncthreads();
        int gn = (j < NP) ? g * NP + j : NORI + g;
        const unsigned short* kb = p.qkv + (size_t)gn * 1536 + hh * DKH;
        short8 k8 = *(const short8*)(kb + 512 + c0);
        short8 v8 = *(const short8*)(kb + 1024 + c0);
        #pragma unroll
        for (int t = 0; t < 8; ++t) {
            Ks[j][c0 + t] = bf2f((unsigned short)k8[t]);
            Vs[j][c0 + t] = bf2f((unsigned short)v8[t]);
        }
        if (tid < 64) Qs[tid] = bf2f(p.qkv[(size_t)(NORI + g) * 1536 + hh * DKH + tid]);
        __syncthreads();
        if (tid < 64) {
            float s;
            if (tid < 32) {
                float dot = 0.0f;
                #pragma unroll
                for (int k = 0; k < 64; ++k) dot += Qs[k] * Ks[tid][k];
                s = dot * 0.125f + p.Bg[(size_t)g * 1024 + 31 * 32 + tid];
            } else s = -1e30f;
            float mx = s;
            #pragma unroll
            for (int off = 32; off > 0; off >>= 1) mx = fmaxf(mx, __shfl_xor(mx, off));
            float e = (tid < 32) ? __expf(s - mx) : 0.0f;
            float sum = e;
            #pragma unroll
            for (int off = 32; off > 0; off >>= 1) sum += __shfl_xor(sum, off);
            if (tid < 32) Pp[tid] = e / sum;
        }
        __syncthreads();
        if (tid < 64) {
            float acc = 0.0f;
            #pragma unroll
            for (int jj = 0; jj < 32; ++jj) acc += Pp[jj] * Vs[jj][tid];
            p.o[(size_t)(NORI + g) * DIM + hh * DKH + tid] = f2bf(acc);
        }
        __syncthreads();
    }
}

// ---------------------------------------------------------------- mega kernel
__global__ __launch_bounds__(256, 2) void mega(MP p)
{
    __shared__ __align__(16) char smem[32768];
    unsigned ep = 0;

    // stage 0: prep (init_h+B, QKV weight transpose, Wo/W1/W2 transpose)
    for (int u = blockIdx.x; u < 2112 + 3096 + 9216; u += GRID) {
        __syncthreads();
        if (u < 2112)      prep_inith_unit(p, u, smem);
        else if (u < 5208) prep_qkv_unit(p, u - 2112, smem);
        else               prep_w_unit(p, u - 5208, smem);
    }
    gbar(p.bar, ++ep);

    for (int l = 0; l < NLAY; ++l) {
        const bool last = (l == NLAY - 1);
        stage_ln(p, 0, NT, false, smem);
        gbar(p.bar, ++ep);
        stage_gemm128(p.hn, p.Wqkv_t + (size_t)l * 1536 * DIM, p.bqkv + l * 1536,
                      p.qkv, 1536, DIM, last ? 6 : 2, 16, 12, 1, smem);
        gbar(p.bar, ++ep);
        if (!last) stage_attn(p, smem);
        else       stage_attn_last(p, smem);
        gbar(p.bar, ++ep);
        if (!last)
            stage_gemm128(p.o, p.Wo_t + (size_t)l * DIM * DIM, p.bo + l * DIM,
                          p.h, DIM, DIM, 0, 16, 4, 4, smem);
        else
            stage_gemm64(p.o, p.Wo_t + (size_t)l * DIM * DIM, p.bo + l * DIM,
                         p.h, DIM, DIM, NORI, 0, 1, 8, 8, 0, smem);
        gbar(p.bar, ++ep);
        stage_ln(p, last ? NORI : 0, last ? NG : NT, last, smem);
        gbar(p.bar, ++ep);
        if (!last)
            stage_gemm128(p.hn, p.W1_t + (size_t)l * FFD * DIM, p.b1 + l * FFD,
                          p.qkv, FFD, DIM, 3, 16, 16, 1, smem);
        else
            stage_gemm64(p.hn, p.W1_t + (size_t)l * FFD * DIM, p.b1 + l * FFD,
                         p.qkv, FFD, DIM, NORI, 3, 1, 32, 1, 0, smem);
        gbar(p.bar, ++ep);
        if (!last)
            stage_gemm128(p.qkv, p.W2_t + (size_t)l * DIM * FFD, p.b2 + l * DIM,
                          p.h, DIM, FFD, 0, 16, 4, 4, smem);
        else
            stage_gemm64(p.qkv, p.W2_t + (size_t)l * DIM * FFD, p.b2 + l * DIM,
                         p.out, DIM, FFD, NORI, 0, 1, 8, 8, NORI, smem);
        if (!last) gbar(p.bar, ++ep);
    }
}

// ---------------------------------------------------------------- launch
extern "C" void kernel_launch(void* const* d_in, const int* in_sizes, int n_in,
                              void* d_out, int out_size, void* d_ws, size_t ws_size,
                              hipStream_t stream)
{
    MP p;
    p.x        = (const float*)d_in[0];
    p.sp       = (const int*)d_in[1];
    p.degrees  = (const int*)d_in[3];
    p.init_W   = (const float*)d_in[4];
    p.init_b   = (const float*)d_in[5];
    p.cent_emb = (const float*)d_in[6];
    p.db       = (const float*)d_in[7];
    p.vbias    = (const float*)d_in[8];
    p.Wq       = (const float*)d_in[9];
    p.bq       = (const float*)d_in[10];
    p.Wk       = (const float*)d_in[11];
    p.bk       = (const float*)d_in[12];
    p.Wv       = (const float*)d_in[13];
    p.bv       = (const float*)d_in[14];
    p.Wo       = (const float*)d_in[15];
    p.bo       = (const float*)d_in[16];
    p.W1       = (const float*)d_in[17];
    p.b1       = (const float*)d_in[18];
    p.W2       = (const float*)d_in[19];
    p.b2       = (const float*)d_in[20];

    char* ws = (char*)d_ws;
    p.h      = (float*)ws;          ws += (size_t)NT * DIM * 4;
    p.hn     = (unsigned short*)ws; ws += (size_t)NT * DIM * 2;
    p.o      = (unsigned short*)ws; ws += (size_t)NT * DIM * 2;
    p.qkv    = (unsigned short*)ws; ws += (size_t)NT * FFD * 2;      // aliased qkv/ffn
    p.Bg     = (float*)ws;          ws += (size_t)NG * 1024 * 4;
    p.Wqkv_t = (unsigned short*)ws; ws += (size_t)NLAY * 1536 * DIM * 2;
    p.Wo_t   = (unsigned short*)ws; ws += (size_t)NLAY * DIM * DIM * 2;
    p.W1_t   = (unsigned short*)ws; ws += (size_t)NLAY * FFD * DIM * 2;
    p.W2_t   = (unsigned short*)ws; ws += (size_t)NLAY * DIM * FFD * 2;
    p.bqkv   = (float*)ws;          ws += (size_t)NLAY * 1536 * 4;
    p.bar    = (unsigned*)ws;       ws += 16384;
    p.out    = (float*)d_out;

    bar_init<<<1, 256, 0, stream>>>(p.bar);
    mega<<<GRID, 256, 0, stream>>>(p);
}

// Round 8
// 452.456 us; speedup vs baseline: 3.6567x; 1.8632x over previous
//
#include <hip/hip_runtime.h>

// Graphormer encoder — bf16 MFMA GEMMs, fp32 residual path. Multi-dispatch.
// R16: mega-kernel abandoned (3 rounds: in-kernel grid barriers cost >= a
// dispatch gap each + L2 fence thrash; best mega 672us vs 457us pipeline).
// Back to the verified R9 pipeline with dispatch-count reductions:
//   - prep merged 3 -> 1 kernel (block-range demux)
//   - final memcpy removed: last LN seeds d_out with residual, last FFN2
//     atomically accumulates into d_out (orow-rebased) — both mega-verified.
// 32 -> 29 dispatches.

#define NG   64
#define NP   31
#define NORI 1984
#define NT   2048
#define DIM  512
#define NHD  8
#define DKH  64
#define FFD  2048
#define NLAY 4
#define NFEA 32

typedef __attribute__((ext_vector_type(8))) short short8;
typedef __attribute__((ext_vector_type(4))) float floatx4;

__device__ __forceinline__ unsigned short f2bf(float f) {
    union { float f; unsigned u; } v; v.f = f;
    unsigned r = v.u + 0x7fffu + ((v.u >> 16) & 1u);
    return (unsigned short)(r >> 16);
}
__device__ __forceinline__ float bf2f(unsigned short u) {
    union { unsigned u; float f; } v; v.u = ((unsigned)u) << 16;
    return v.f;
}

// ---------------------------------------------------------------- merged prep (1 dispatch)
// blocks [0,2112): init_h rows / B-build; [2112,5208): QKV transpose+bias;
// [5208,14424): Wo/W1/W2 transpose.
__global__ __launch_bounds__(256) void prep_all(
    const float* __restrict__ x, const int* __restrict__ degrees,
    const float* __restrict__ init_W, const float* __restrict__ init_b,
    const float* __restrict__ cent_emb, float* __restrict__ h,
    const int* __restrict__ sp, const float* __restrict__ db,
    const float* __restrict__ virt_bias, float* __restrict__ Bg,
    const float* __restrict__ Wq, const float* __restrict__ Wk,
    const float* __restrict__ Wv, const float* __restrict__ bq,
    const float* __restrict__ bk, const float* __restrict__ bv,
    unsigned short* __restrict__ Wqkv_t, float* __restrict__ bqkv,
    const float* __restrict__ Wo, const float* __restrict__ W1,
    const float* __restrict__ W2, unsigned short* __restrict__ Wo_t,
    unsigned short* __restrict__ W1_t, unsigned short* __restrict__ W2_t)
{
    __shared__ float tl[32][33];
    int u = blockIdx.x;
    int tid = threadIdx.x;

    if (u < 2112) {                       // ---- init_h + build_B
        int n = u;
        if (n >= NT) {                    // B-build: one block per graph
            int g = n - NT;
            float vb = virt_bias[0];
            for (int e = tid; e < 1024; e += 256) {
                int i = e >> 5, j = e & 31;
                float v;
                if (i == j) v = db[0];
                else if (i < NP && j < NP) {
                    int s = sp[(size_t)(g * NP + i) * NORI + g * NP + j];
                    v = db[s < 100 ? s : 100];
                } else v = vb;
                Bg[(size_t)g * 1024 + e] = v;
            }
            return;
        }
        float* xs = &tl[0][0];
        if (n < NORI && tid < NFEA) xs[tid] = x[(size_t)n * NFEA + tid];
        __syncthreads();
        int deg = degrees[n]; if (deg > 100) deg = 100;
        for (int d = tid; d < DIM; d += 256) {
            float v = cent_emb[(size_t)deg * DIM + d];
            if (n < NORI) {
                float acc = init_b[d];
                #pragma unroll
                for (int k = 0; k < NFEA; ++k) acc += xs[k] * init_W[(size_t)k * DIM + d];
                v += acc;
            }
            h[(size_t)n * DIM + d] = v;
        }
        return;
    }
    if (u < 5208) {                       // ---- QKV weight transpose + bias
        int tile = u - 2112;
        if (tile >= 3072) {               // bias part: 24 blocks cover NLAY*1536
            int idx = (tile - 3072) * 256 + tid;
            if (idx < NLAY * 1536) {
                int l = idx / 1536, c = idx % 1536;
                int which = c >> 9, cc = c & 511;
                const float* b = (which == 0) ? bq : (which == 1) ? bk : bv;
                bqkv[idx] = b[(size_t)l * 512 + cc];
            }
            return;
        }
        int slice = tile >> 5;
        int tloc = tile & 31;
        int dt = tloc >> 1, kt = tloc & 1;
        int l = slice / 24; int rem = slice % 24; int which = rem >> 3; int hh = rem & 7;
        const float* W = (which == 0) ? Wq : (which == 1) ? Wk : Wv;
        const float* in = W + (size_t)(l * 8 + hh) * DIM * DKH;
        int tr = tid >> 5, tc = tid & 31;
        #pragma unroll
        for (int pp = 0; pp < 4; ++pp)
            tl[tr + pp * 8][tc] = in[(size_t)(dt * 32 + tr + pp * 8) * DKH + kt * 32 + tc];
        __syncthreads();
        unsigned short* out = Wqkv_t +
            ((size_t)l * 1536 + which * 512 + hh * 64 + kt * 32) * DIM + dt * 32;
        #pragma unroll
        for (int pp = 0; pp < 4; ++pp)
            out[(size_t)(tr + pp * 8) * DIM + tc] = f2bf(tl[tc][tr + pp * 8]);
        return;
    }
    {                                     // ---- Wo/W1/W2 transpose
        int id = u - 5208;
        const float* in; unsigned short* outp; int R, C, l, rt, ct;
        if (id < 1024) {
            l = id >> 8; int t = id & 255; rt = t >> 4; ct = t & 15;
            in = Wo; outp = Wo_t; R = 512; C = 512;
        } else if (id < 5120) {
            int t2 = id - 1024; l = t2 >> 10; int t = t2 & 1023; rt = t >> 6; ct = t & 63;
            in = W1; outp = W1_t; R = 512; C = 2048;
        } else {
            int t2 = id - 5120; l = t2 >> 10; int t = t2 & 1023; rt = t >> 4; ct = t & 15;
            in = W2; outp = W2_t; R = 2048; C = 512;
        }
        const float* ip = in + (size_t)l * R * C;
        unsigned short* op = outp + (size_t)l * R * C;
        int r0 = rt * 32, c0 = ct * 32;
        int tr = tid >> 5, tc = tid & 31;
        #pragma unroll
        for (int pp = 0; pp < 4; ++pp)
            tl[tr + pp * 8][tc] = ip[(size_t)(r0 + tr + pp * 8) * C + c0 + tc];
        __syncthreads();
        #pragma unroll
        for (int pp = 0; pp < 4; ++pp)
            op[(size_t)(c0 + tr + pp * 8) * R + r0 + tc] = f2bf(tl[tc][tr + pp * 8]);
    }
}

// ---------------------------------------------------------------- layernorm: fp32 in -> bf16 out
// fout != nullptr: also copy the raw fp32 row to fout[(n-row0)*DIM+..] (d_out seeding)
__global__ __launch_bounds__(256) void layernorm_bf16(
    const float* __restrict__ in, unsigned short* __restrict__ out, int row0,
    float* __restrict__ fout)
{
    int n = row0 + blockIdx.x;
    int tid = threadIdx.x;
    const float* row = in + (size_t)n * DIM;
    float v0 = row[tid], v1 = row[tid + 256];
    float s = v0 + v1;
    float sq = v0 * v0 + v1 * v1;
    #pragma unroll
    for (int off = 32; off > 0; off >>= 1) {
        s  += __shfl_down(s, off);
        sq += __shfl_down(sq, off);
    }
    __shared__ float red[8];
    int wave = tid >> 6;
    if ((tid & 63) == 0) { red[wave] = s; red[4 + wave] = sq; }
    __syncthreads();
    float ts  = red[0] + red[1] + red[2] + red[3];
    float tsq = red[4] + red[5] + red[6] + red[7];
    float m   = ts * (1.0f / DIM);
    float var = tsq * (1.0f / DIM) - m * m;
    float inv = rsqrtf(var + 1e-5f);
    out[(size_t)n * DIM + tid]       = f2bf((v0 - m) * inv);
    out[(size_t)n * DIM + tid + 256] = f2bf((v1 - m) * inv);
    if (fout) {
        fout[(size_t)(n - row0) * DIM + tid]       = v0;
        fout[(size_t)(n - row0) * DIM + tid + 256] = v1;
    }
}

// ---------------------------------------------------------------- bf16 MFMA GEMM, 64-tile (small M)
// C = A@Bt^T. Tile 64x64x64, 256 thr, wave = 32x32 (2x2 frags). 1-D grid P*C*SPLITK.
// orow: subtracted from output row index (write into a buffer starting at row orow).
template<int SPLITK>
__global__ __launch_bounds__(256) void gemm64(
    const unsigned short* __restrict__ A, const unsigned short* __restrict__ Bt,
    const float* __restrict__ bias, void* __restrict__ out,
    int Nfull, int K, int moff, int flags, int P, int C, int orow)
{
    __shared__ __align__(16) unsigned short Asl[64 * 72];
    __shared__ __align__(16) unsigned short Bsl[64 * 72];
    int id = blockIdx.x;
    int by, bx, bz;
    if (P >= 8) {
        int xcd = id & 7, t = id >> 3, G = P >> 3;
        by = xcd + 8 * (t % G);
        int r2 = t / G;
        bx = r2 % C;
        bz = r2 / C;
    } else {
        by = id % P; int r2 = id / P; bx = r2 % C; bz = r2 / C;
    }
    int tid = threadIdx.x;
    int row0 = moff + by * 64, col0 = bx * 64;
    if ((flags & 4) && col0 < 512 && row0 < NORI) return;
    int kslice = K / SPLITK;
    int kbeg = bz * kslice;
    int wave = tid >> 6, lane = tid & 63;
    int quad = lane >> 4, m16 = lane & 15;
    int mw = (wave >> 1) * 32, nw = (wave & 1) * 32;
    floatx4 acc[2][2] = {};
    for (int k0 = kbeg; k0 < kbeg + kslice; k0 += 64) {
        #pragma unroll
        for (int p = 0; p < 2; ++p) {
            int idx = (p * 256 + tid) * 8;
            int r = idx >> 6, kk = idx & 63;
            *(float4*)(Asl + r * 72 + kk) =
                *(const float4*)(A + (size_t)(row0 + r) * K + k0 + kk);
            *(float4*)(Bsl + r * 72 + kk) =
                *(const float4*)(Bt + (size_t)(col0 + r) * K + k0 + kk);
        }
        __syncthreads();
        #pragma unroll
        for (int ks = 0; ks < 64; ks += 32) {
            short8 a[2], b[2];
            #pragma unroll
            for (int mi = 0; mi < 2; ++mi)
                a[mi] = *(const short8*)(Asl + (mw + mi * 16 + m16) * 72 + ks + quad * 8);
            #pragma unroll
            for (int ni = 0; ni < 2; ++ni)
                b[ni] = *(const short8*)(Bsl + (nw + ni * 16 + m16) * 72 + ks + quad * 8);
            #pragma unroll
            for (int mi = 0; mi < 2; ++mi)
                #pragma unroll
                for (int ni = 0; ni < 2; ++ni)
                    acc[mi][ni] = __builtin_amdgcn_mfma_f32_16x16x32_bf16(
                        a[mi], b[ni], acc[mi][ni], 0, 0, 0);
        }
        __syncthreads();
    }
    if (SPLITK == 1) {
        int do_relu = flags & 1, out_bf = flags & 2;
        #pragma unroll
        for (int mi = 0; mi < 2; ++mi) {
            #pragma unroll
            for (int ni = 0; ni < 2; ++ni) {
                int col = col0 + nw + ni * 16 + m16;
                float bval = bias[col];
                #pragma unroll
                for (int rr = 0; rr < 4; ++rr) {
                    int row = row0 + mw + mi * 16 + quad * 4 + rr;
                    float v = acc[mi][ni][rr] + bval;
                    if (do_relu) v = fmaxf(v, 0.0f);
                    if (out_bf) ((unsigned short*)out)[(size_t)(row - orow) * Nfull + col] = f2bf(v);
                    else        ((float*)out)[(size_t)(row - orow) * Nfull + col] = v;
                }
            }
        }
    } else {
        float* o = (float*)out;
        float bscale = (bz == 0) ? 1.0f : 0.0f;
        #pragma unroll
        for (int mi = 0; mi < 2; ++mi) {
            #pragma unroll
            for (int ni = 0; ni < 2; ++ni) {
                int col = col0 + nw + ni * 16 + m16;
                float bval = bias[col] * bscale;
                #pragma unroll
                for (int rr = 0; rr < 4; ++rr) {
                    int row = row0 + mw + mi * 16 + quad * 4 + rr;
                    atomicAdd(&o[(size_t)(row - orow) * Nfull + col],
                              acc[mi][ni][rr] + bval);
                }
            }
        }
    }
}

// ---------------------------------------------------------------- bf16 MFMA GEMM, 128-tile (m97)
template<int SPLITK>
__global__ __launch_bounds__(256) void gemm128(
    const unsigned short* __restrict__ A, const unsigned short* __restrict__ Bt,
    const float* __restrict__ bias, void* __restrict__ out,
    int Nfull, int K, int flags, int P, int C)
{
    __shared__ __align__(16) unsigned short Asl[128 * 64];
    __shared__ __align__(16) unsigned short Bsl[128 * 64];
    int id = blockIdx.x;
    int xcd = id & 7, t = id >> 3, Gp = P >> 3;
    int by = xcd + 8 * (t % Gp);
    int r2 = t / Gp;
    int bx = r2 % C;
    int bz = r2 / C;
    int tid = threadIdx.x;
    int row0 = by * 128, col0 = bx * 128;
    if ((flags & 4) && col0 < 512 && row0 + 128 <= NORI) return;   // Q only for virt panel
    int kslice = K / SPLITK;
    int kbeg = bz * kslice;
    int wave = tid >> 6, lane = tid & 63;
    int quad = lane >> 4, m16 = lane & 15;
    int mw = (wave >> 1) * 64, nw = (wave & 1) * 64;
    int lr = lane >> 3;
    int srcswz = ((lane & 7) ^ lr) << 3;
    int rdswz = (m16 & 7) << 4;
    const unsigned short* Abase = A + (size_t)row0 * K;
    const unsigned short* Bbase = Bt + (size_t)col0 * K;
    floatx4 acc[4][4] = {};
    for (int k0 = kbeg; k0 < kbeg + kslice; k0 += 64) {
        #pragma unroll
        for (int p = 0; p < 4; ++p) {
            int chunk = wave * 4 + p;
            int r = chunk * 8 + lr;
            __builtin_amdgcn_global_load_lds(
                (const __attribute__((address_space(1))) unsigned int*)
                    (Abase + (size_t)r * K + k0 + srcswz),
                (__attribute__((address_space(3))) unsigned int*)
                    (Asl + chunk * 512 + lane * 8), 16, 0, 0);
            __builtin_amdgcn_global_load_lds(
                (const __attribute__((address_space(1))) unsigned int*)
                    (Bbase + (size_t)r * K + k0 + srcswz),
                (__attribute__((address_space(3))) unsigned int*)
                    (Bsl + chunk * 512 + lane * 8), 16, 0, 0);
        }
        __syncthreads();
        #pragma unroll
        for (int ks = 0; ks < 64; ks += 32) {
            short8 a[4], b[4];
            int cb = (ks + quad * 8) * 2;
            #pragma unroll
            for (int mi = 0; mi < 4; ++mi)
                a[mi] = *(const short8*)((const char*)Asl +
                        (mw + mi * 16 + m16) * 128 + (cb ^ rdswz));
            #pragma unroll
            for (int ni = 0; ni < 4; ++ni)
                b[ni] = *(const short8*)((const char*)Bsl +
                        (nw + ni * 16 + m16) * 128 + (cb ^ rdswz));
            #pragma unroll
            for (int mi = 0; mi < 4; ++mi)
                #pragma unroll
                for (int ni = 0; ni < 4; ++ni)
                    acc[mi][ni] = __builtin_amdgcn_mfma_f32_16x16x32_bf16(
                        a[mi], b[ni], acc[mi][ni], 0, 0, 0);
        }
        __syncthreads();
    }
    if (SPLITK == 1) {
        int do_relu = flags & 1, out_bf = flags & 2;
        #pragma unroll
        for (int mi = 0; mi < 4; ++mi) {
            #pragma unroll
            for (int ni = 0; ni < 4; ++ni) {
                int col = col0 + nw + ni * 16 + m16;
                float bval = bias[col];
                #pragma unroll
                for (int rr = 0; rr < 4; ++rr) {
                    int row = row0 + mw + mi * 16 + quad * 4 + rr;
                    float v = acc[mi][ni][rr] + bval;
                    if (do_relu) v = fmaxf(v, 0.0f);
                    if (out_bf) ((unsigned short*)out)[(size_t)row * Nfull + col] = f2bf(v);
                    else        ((float*)out)[(size_t)row * Nfull + col] = v;
                }
            }
        }
    } else {
        float* o = (float*)out;
        float bscale = (bz == 0) ? 1.0f : 0.0f;
        #pragma unroll
        for (int mi = 0; mi < 4; ++mi) {
            #pragma unroll
            for (int ni = 0; ni < 4; ++ni) {
                int col = col0 + nw + ni * 16 + m16;
                float bval = bias[col] * bscale;
                #pragma unroll
                for (int rr = 0; rr < 4; ++rr) {
                    int row = row0 + mw + mi * 16 + quad * 4 + rr;
                    atomicAdd(&o[(size_t)row * Nfull + col], acc[mi][ni][rr] + bval);
                }
            }
        }
    }
}

// ---------------------------------------------------------------- block attention (layers 0..2)
__global__ __launch_bounds__(256) void attention(
    const unsigned short* __restrict__ qkv,  // [NT][1536] bf16, Q|K|V head-major
    const float* __restrict__ Bg,            // [NG][32][32]
    unsigned short* __restrict__ O)          // [NT][512] bf16 head-major
{
    int g = blockIdx.x >> 3;
    int hh = blockIdx.x & 7;
    __shared__ float Qs[32][65], Ks[32][65], Vs[32][65];
    __shared__ float S[32][33];
    int tid = threadIdx.x;
    int i = tid >> 3;
    int c0 = (tid & 7) * 8;
    int gn = (i < NP) ? g * NP + i : NORI + g;
    const unsigned short* base = qkv + (size_t)gn * 1536 + hh * DKH;
    short8 qv = *(const short8*)(base + c0);
    short8 kv = *(const short8*)(base + 512 + c0);
    short8 vv = *(const short8*)(base + 1024 + c0);
    #pragma unroll
    for (int j = 0; j < 8; ++j) {
        Qs[i][c0 + j] = bf2f((unsigned short)qv[j]);
        Ks[i][c0 + j] = bf2f((unsigned short)kv[j]);
        Vs[i][c0 + j] = bf2f((unsigned short)vv[j]);
    }
    __syncthreads();
    const float scale = 0.125f;
    #pragma unroll
    for (int e = 0; e < 4; ++e) {
        int idx = tid + e * 256;
        int si = idx >> 5, sj = idx & 31;
        float dot = 0.0f;
        #pragma unroll
        for (int k = 0; k < DKH; ++k) dot += Qs[si][k] * Ks[sj][k];
        S[si][sj] = dot * scale + Bg[(size_t)g * 1024 + si * 32 + sj];
    }
    __syncthreads();
    if (tid < 32) {
        float mx = -1e30f;
        #pragma unroll
        for (int j = 0; j < 32; ++j) mx = fmaxf(mx, S[tid][j]);
        float sum = 0.0f;
        #pragma unroll
        for (int j = 0; j < 32; ++j) { float e = __expf(S[tid][j] - mx); S[tid][j] = e; sum += e; }
        float inv = 1.0f / sum;
        #pragma unroll
        for (int j = 0; j < 32; ++j) S[tid][j] *= inv;
    }
    __syncthreads();
    short8 ov;
    #pragma unroll
    for (int cc = 0; cc < 8; ++cc) {
        float acc = 0.0f;
        #pragma unroll
        for (int j = 0; j < 32; ++j) acc += S[i][j] * Vs[j][c0 + cc];
        ov[cc] = (short)f2bf(acc);
    }
    *(short8*)(O + (size_t)gn * DIM + hh * DKH + c0) = ov;
}

// ---------------------------------------------------------------- last-layer attention
__global__ __launch_bounds__(64) void attention_last(
    const unsigned short* __restrict__ qkv, const float* __restrict__ Bg,
    unsigned short* __restrict__ O)
{
    int g = blockIdx.x >> 3, hh = blockIdx.x & 7;
    __shared__ float Ks[32][65], Vs[32][65];
    __shared__ float Qs[64], P[32];
    int tid = threadIdx.x;
    int j = tid & 31, hf = tid >> 5;
    int gn = (j < NP) ? g * NP + j : NORI + g;
    const unsigned short* kb = qkv + (size_t)gn * 1536 + hh * DKH + 512 + hf * 32;
    #pragma unroll
    for (int c = 0; c < 32; c += 8) {
        short8 k8 = *(const short8*)(kb + c);
        short8 v8 = *(const short8*)(kb + 512 + c);
        #pragma unroll
        for (int t = 0; t < 8; ++t) {
            Ks[j][hf * 32 + c + t] = bf2f((unsigned short)k8[t]);
            Vs[j][hf * 32 + c + t] = bf2f((unsigned short)v8[t]);
        }
    }
    Qs[tid] = bf2f(qkv[(size_t)(NORI + g) * 1536 + hh * DKH + tid]);
    __syncthreads();
    float s;
    if (tid < 32) {
        float dot = 0.0f;
        #pragma unroll
        for (int k = 0; k < 64; ++k) dot += Qs[k] * Ks[tid][k];
        s = dot * 0.125f + Bg[(size_t)g * 1024 + 31 * 32 + tid];
    } else s = -1e30f;
    float mx = s;
    #pragma unroll
    for (int off = 32; off > 0; off >>= 1) mx = fmaxf(mx, __shfl_xor(mx, off));
    float e = (tid < 32) ? __expf(s - mx) : 0.0f;
    float sum = e;
    #pragma unroll
    for (int off = 32; off > 0; off >>= 1) sum += __shfl_xor(sum, off);
    if (tid < 32) P[tid] = e / sum;
    __syncthreads();
    float acc = 0.0f;
    #pragma unroll
    for (int jj = 0; jj < 32; ++jj) acc += P[jj] * Vs[jj][tid];
    O[(size_t)(NORI + g) * DIM + hh * DKH + tid] = f2bf(acc);
}

// ---------------------------------------------------------------- launch
extern "C" void kernel_launch(void* const* d_in, const int* in_sizes, int n_in,
                              void* d_out, int out_size, void* d_ws, size_t ws_size,
                              hipStream_t stream)
{
    const float* x        = (const float*)d_in[0];
    const int*   sp       = (const int*)d_in[1];
    const int*   degrees  = (const int*)d_in[3];
    const float* init_W   = (const float*)d_in[4];
    const float* init_b   = (const float*)d_in[5];
    const float* cent_emb = (const float*)d_in[6];
    const float* db       = (const float*)d_in[7];
    const float* vbias    = (const float*)d_in[8];
    const float* Wq       = (const float*)d_in[9];
    const float* bq       = (const float*)d_in[10];
    const float* Wk       = (const float*)d_in[11];
    const float* bk       = (const float*)d_in[12];
    const float* Wv       = (const float*)d_in[13];
    const float* bv       = (const float*)d_in[14];
    const float* Wo       = (const float*)d_in[15];
    const float* bo       = (const float*)d_in[16];
    const float* W1       = (const float*)d_in[17];
    const float* b1       = (const float*)d_in[18];
    const float* W2       = (const float*)d_in[19];
    const float* b2       = (const float*)d_in[20];

    char* ws = (char*)d_ws;
    float*          h      = (float*)ws;          ws += (size_t)NT * DIM * 4;
    unsigned short* hn     = (unsigned short*)ws; ws += (size_t)NT * DIM * 2;
    unsigned short* o      = (unsigned short*)ws; ws += (size_t)NT * DIM * 2;
    unsigned short* qkv    = (unsigned short*)ws; ws += (size_t)NT * FFD * 2;      // aliased qkv/ffn
    float*          Bg     = (float*)ws;          ws += (size_t)NG * 1024 * 4;
    unsigned short* Wqkv_t = (unsigned short*)ws; ws += (size_t)NLAY * 1536 * DIM * 2;
    unsigned short* Wo_t   = (unsigned short*)ws; ws += (size_t)NLAY * DIM * DIM * 2;
    unsigned short* W1_t   = (unsigned short*)ws; ws += (size_t)NLAY * FFD * DIM * 2;
    unsigned short* W2_t   = (unsigned short*)ws; ws += (size_t)NLAY * DIM * FFD * 2;
    float*          bqkv   = (float*)ws;          ws += (size_t)NLAY * 1536 * 4;
    unsigned short* ffnb   = qkv;

    // prep (1 launch)
    prep_all<<<14424, 256, 0, stream>>>(
        x, degrees, init_W, init_b, cent_emb, h, sp, db, vbias, Bg,
        Wq, Wk, Wv, bq, bk, bv, Wqkv_t, bqkv, Wo, W1, W2, Wo_t, W1_t, W2_t);

    for (int l = 0; l < NLAY - 1; ++l) {
        layernorm_bf16<<<NT, 256, 0, stream>>>(h, hn, 0, nullptr);
        gemm128<1><<<16 * 12, 256, 0, stream>>>(
            hn, Wqkv_t + (size_t)l * 1536 * DIM, bqkv + (size_t)l * 1536,
            qkv, 1536, DIM, /*bf16 out*/2, 16, 12);
        attention<<<NG * NHD, 256, 0, stream>>>(qkv, Bg, o);
        gemm128<2><<<16 * 4 * 2, 256, 0, stream>>>(
            o, Wo_t + (size_t)l * DIM * DIM, bo + (size_t)l * DIM,
            h, DIM, DIM, 0, 16, 4);
        layernorm_bf16<<<NT, 256, 0, stream>>>(h, hn, 0, nullptr);
        gemm128<1><<<16 * 16, 256, 0, stream>>>(
            hn, W1_t + (size_t)l * FFD * DIM, b1 + (size_t)l * FFD,
            ffnb, FFD, DIM, /*relu+bf16*/3, 16, 16);
        gemm128<4><<<16 * 4 * 4, 256, 0, stream>>>(
            ffnb, W2_t + (size_t)l * DIM * FFD, b2 + (size_t)l * DIM,
            h, DIM, FFD, 0, 16, 4);
    }

    // ---- last layer: only virtual rows reach the output ----
    {
        int l = NLAY - 1;
        layernorm_bf16<<<NT, 256, 0, stream>>>(h, hn, 0, nullptr);
        // K,V for all rows; Q only for the panel containing virtual rows (flag 4)
        gemm128<1><<<16 * 12, 256, 0, stream>>>(
            hn, Wqkv_t + (size_t)l * 1536 * DIM, bqkv + (size_t)l * 1536,
            qkv, 1536, DIM, /*bf16 out + lastQKV*/6, 16, 12);
        attention_last<<<NG * NHD, 64, 0, stream>>>(qkv, Bg, o);
        gemm64<8><<<1 * 8 * 8, 256, 0, stream>>>(
            o, Wo_t + (size_t)l * DIM * DIM, bo + (size_t)l * DIM,
            h, DIM, DIM, NORI, 0, 1, 8, 0);
        // LN over virtual rows; seed d_out with the fp32 residual rows
        layernorm_bf16<<<NG, 256, 0, stream>>>(h, hn, NORI, (float*)d_out);
        gemm64<1><<<1 * 32, 256, 0, stream>>>(
            hn, W1_t + (size_t)l * FFD * DIM, b1 + (size_t)l * FFD,
            ffnb, FFD, DIM, NORI, 3, 1, 32, 0);
        // FFN2 accumulates directly into d_out (residual already there)
        gemm64<8><<<1 * 8 * 8, 256, 0, stream>>>(
            ffnb, W2_t + (size_t)l * DIM * FFD, b2 + (size_t)l * DIM,
            d_out, DIM, FFD, NORI, 0, 1, 8, NORI);
    }
}